// Round 11
// baseline (3507.887 us; speedup 1.0000x reference)
//
#include <hip/hip_runtime.h>
#include <stdint.h>

#define AGENT __HIP_MEMORY_SCOPE_AGENT
typedef unsigned long long u64;

// x[64][256][256] -> xT[t][k][b]  (k-major, batch-minor)
__global__ __launch_bounds__(256) void xpose_in(const float* __restrict__ x,
                                                float* __restrict__ xT) {
  const int t = blockIdx.x;
  const int b = threadIdx.x & 63;
  const int w = threadIdx.x >> 6;
  const float* xr = x + ((size_t)b * 256 + t) * 256;
  float* o = xT + (size_t)t * 256 * 64;
  for (int kq = w * 16; kq < w * 16 + 16; ++kq) {
    float4 v = *(const float4*)(xr + kq * 4);
    o[(size_t)(kq * 4 + 0) * 64 + b] = v.x;
    o[(size_t)(kq * 4 + 1) * 64 + b] = v.y;
    o[(size_t)(kq * 4 + 2) * 64 + b] = v.z;
    o[(size_t)(kq * 4 + 3) * 64 + b] = v.w;
  }
}

// Pack [W;U] ([KT][4H]) into quad-major per-WG blocks:
//   out[((wg*KTq + q)*16 + c)*4 + j] = WU[k=4q+j][col = g*H + wg*4 + jl],
// c = g*4 + jl. (Global layout unchanged; bank-conflict fix applied at
// LDS-staging time in the worker.)
__global__ __launch_bounds__(256) void pack_wu(const float* __restrict__ W,
                                               const float* __restrict__ U,
                                               float* __restrict__ out,
                                               int DIN, int H) {
  __shared__ float tile[64][65];
  const int KT = DIN + H;
  const int KTq = KT >> 2;
  const int c0 = blockIdx.x * 64;
  const int k0 = blockIdx.y * 64;
  const int tx = threadIdx.x & 63;
  const int ty = threadIdx.x >> 6;
  for (int r = ty; r < 64; r += 4) {
    const int k = k0 + r;
    tile[r][tx] = (k < DIN) ? W[(size_t)k * (4 * H) + c0 + tx]
                            : U[(size_t)(k - DIN) * (4 * H) + c0 + tx];
  }
  __syncthreads();
  for (int r = ty; r < 64; r += 4) {
    const int cg = c0 + r;
    const int g = cg / H;
    const int col = cg - g * H;
    const int wg = col >> 2;
    const int jl = col & 3;
    const int c = (g << 2) | jl;
    const int k = k0 + tx;
    const int q = k >> 2;
    const int j = k & 3;
    out[(((size_t)wg * KTq + q) * 16 + c) * 4 + j] = tile[tx][r];
  }
}

#define SB __builtin_amdgcn_sched_barrier(0)
// Round-1 lesson: macro params must NOT be named x/y/z/w (member capture).
// 8 fmas: one w-scalar WS_ times 8 batch values (two float4 halves).
#define FMA_B8(I_, WS_, XA_, XB_)                                   \
  acc[(I_) * 8 + 0] = fmaf(WS_, (XA_).x, acc[(I_) * 8 + 0]);        \
  acc[(I_) * 8 + 1] = fmaf(WS_, (XA_).y, acc[(I_) * 8 + 1]);        \
  acc[(I_) * 8 + 2] = fmaf(WS_, (XA_).z, acc[(I_) * 8 + 2]);        \
  acc[(I_) * 8 + 3] = fmaf(WS_, (XA_).w, acc[(I_) * 8 + 3]);        \
  acc[(I_) * 8 + 4] = fmaf(WS_, (XB_).x, acc[(I_) * 8 + 4]);        \
  acc[(I_) * 8 + 5] = fmaf(WS_, (XB_).y, acc[(I_) * 8 + 5]);        \
  acc[(I_) * 8 + 6] = fmaf(WS_, (XB_).z, acc[(I_) * 8 + 6]);        \
  acc[(I_) * 8 + 7] = fmaf(WS_, (XB_).w, acc[(I_) * 8 + 7]);
#define FMA_ROW32(I_, WV_)                 \
  FMA_B8(I_, (WV_).x, x0a_, x0b_)          \
  FMA_B8(I_, (WV_).y, x1a_, x1b_)          \
  FMA_B8(I_, (WV_).z, x2a_, x2b_)          \
  FMA_B8(I_, (WV_).w, x3a_, x3b_)
// One full quad: 8 x-loads + 8 w-reads + 256 FMA, names scoped.
#define QUAD_FMA(SPQ_, WPQ_)                                        \
  {                                                                 \
    const float4 x0a_ = (SPQ_)[0], x0b_ = (SPQ_)[1];                \
    const float4 x1a_ = (SPQ_)[16], x1b_ = (SPQ_)[17];              \
    const float4 x2a_ = (SPQ_)[32], x2b_ = (SPQ_)[33];              \
    const float4 x3a_ = (SPQ_)[48], x3b_ = (SPQ_)[49];              \
    const float4 w0_ = (WPQ_)[0], w1_ = (WPQ_)[1];                  \
    const float4 w2_ = (WPQ_)[2], w3_ = (WPQ_)[3];                  \
    const float4 w4_ = (WPQ_)[4], w5_ = (WPQ_)[5];                  \
    const float4 w6_ = (WPQ_)[6], w7_ = (WPQ_)[7];                  \
    FMA_ROW32(0, w0_)                                               \
    FMA_ROW32(1, w1_)                                               \
    FMA_ROW32(2, w2_)                                               \
    FMA_ROW32(3, w3_)                                               \
    FMA_ROW32(4, w4_)                                               \
    FMA_ROW32(5, w5_)                                               \
    FMA_ROW32(6, w6_)                                               \
    FMA_ROW32(7, w7_)                                               \
  }

// (8c,8b) register tile, 16 FMA/fill; w-LDS bank-swizzled (round-10).
// Round-11: SB region widened to a quad-PAIR with compile-time offsets
// (quad B at sp+64 / wp+17; imm <= 1.8KB global / 384B ds). Round-10's
// per-quad SB forbade cross-quad load hoisting, so each quad ate a full
// load latency and the VALU idled through it (pipes ran sequentially:
// DS 14.7k + VMEM 12.3k + VALU 12.3k ~= the 36k-cyc tick). Now quad B's
// 16 loads hoist above quad A's 256 FMAs -> one exposure per pair and
// DS/VMEM issue under VALU. Registers: 64 acc + ~32 live float4 ~ 200
// (<256 at 2 waves/SIMD). Odd-QL layers (QL=1) take the solo path.
template <int QL>
__device__ __forceinline__ void accum88(const float4* __restrict__ sp,
                                        const float4* __restrict__ wp,
                                        float acc[64]) {
  if constexpr (QL & 1) {
    QUAD_FMA(sp, wp)
    SB;
    sp += 64;
    wp += 17;
  }
#pragma unroll 1
  for (int p = 0; p < QL / 2; ++p) {
    QUAD_FMA(sp, wp)
    QUAD_FMA(sp + 64, wp + 17)
    SB;
    sp += 128;
    wp += 34;
  }
}

// Dedicated per-layer aggregator: one wave gathers this layer's NWG per-WG
// flags for tick t, then publishes a single monotonic epoch word.
template <int NWG>
__device__ __forceinline__ void agg_body(unsigned* __restrict__ flg,
                                         unsigned* __restrict__ ep) {
  const int tid = threadIdx.x;
  if (tid >= 64) return;  // single wave
  for (int t = 0; t < 256; ++t) {
    unsigned* base = flg + (size_t)t * NWG;
    if (NWG <= 64) {
      if (tid < NWG) {
        while (__hip_atomic_load(base + tid, __ATOMIC_RELAXED, AGENT) == 0u)
          __builtin_amdgcn_s_sleep(1);
      }
    } else {
      while (__hip_atomic_load(base + tid, __ATOMIC_RELAXED, AGENT) == 0u)
        __builtin_amdgcn_s_sleep(1);
      while (__hip_atomic_load(base + 64 + tid, __ATOMIC_RELAXED, AGENT) == 0u)
        __builtin_amdgcn_s_sleep(1);
    }
    asm volatile("s_waitcnt vmcnt(0)" ::: "memory");
    if (tid == 0)
      __hip_atomic_store(ep, (unsigned)(t + 1), __ATOMIC_RELAXED, AGENT);
  }
}

// One pipelined LSTM layer. 256-thread WG owns hidden quad wg (4 units);
// weights staged ONCE into LDS, bank-swizzled (<=52KB). 16 K-slices
// (4 waves x 4 intra-wave via lane k4). Intra-wave K-merge (round-11):
// round 1 xor8 via DPP row_ror:8 (VALU pipe — moves 512 swizzles/CU/tick
// off the shared DS pipe; lane^8 == rotate-by-8 within a 16-lane row);
// round 2 xor16 stays ds_swizzle (crosses DPP rows). Same pair-sum order
// as rounds 9/10 -> identical absmax. Then sZ[4] reduction / epilogue /
// publish / flag-epoch sync unchanged.
template <int DIN, int H, int NWG, bool FIN, bool XCOH>
__device__ __forceinline__ void layer_body(
    int wg, int tid, const float* __restrict__ xin, float* __restrict__ hseq,
    const float* __restrict__ wP, const float* __restrict__ bias,
    float* __restrict__ dout, unsigned* __restrict__ selfF,
    unsigned* __restrict__ selfE, unsigned* __restrict__ prevE,
    float* __restrict__ wL, float (*sZ)[16][64], float* sH) {
  constexpr int KT = DIN + H;
  constexpr int KTq = KT / 4;
  constexpr int XQ4 = DIN / 4;         // x quads total
  constexpr int QLX = DIN / 64;        // quads per K-slice (x part)
  constexpr int QLH = H / 64;          // quads per K-slice (h part)
  constexpr int SLABX = QLX * 17 + 2;  // float4s per x slice slab
  constexpr int SLABH = QLH * 17 + 2;  // float4s per h slice slab
  constexpr int T = 256;
  static_assert(DIN % 64 == 0 && H % 64 == 0, "16-way K-slicing");

  const int lane = tid & 63;
  const int wv = tid >> 6;         // wave: K-quarter; unit jl in epilogue
  const int cq = lane >> 5;        // c-half (8 rows)
  const int k4 = (lane >> 3) & 3;  // intra-wave K-slice (lane bits 3-4)
  const int bq = lane & 7;         // batch octet
  const int slice = wv * 4 + k4;   // global K-slice 0..15

  // ---- stage weights into LDS (once), bank-swizzled layout:
  // x part: [slice][q][r] -> slice*SLABX + q*17 + r + (r>>3)
  // h part: 16*SLABX + [slice][q][r] -> ... + slice*SLABH + q*17 + r + (r>>3)
  {
    float4* wl = (float4*)wL;
    const float4* wp = (const float4*)wP + (size_t)wg * KTq * 16;
    for (int i = tid; i < KTq * 16; i += 256) {
      const int qg = i >> 4;
      const int c = i & 15;
      int lidx;
      if (qg < XQ4) {
        lidx = (qg / QLX) * SLABX + (qg % QLX) * 17 + c + (c >> 3);
      } else {
        const int qh = qg - XQ4;
        lidx = 16 * SLABX + (qh / QLH) * SLABH + (qh % QLH) * 17 + c + (c >> 3);
      }
      wl[lidx] = wp[i];
    }
  }
  // read bases: +cq*9 lands on the shifted half for cq=1 (r + (r>>3))
  const float4* wbx = (const float4*)wL + (size_t)slice * SLABX + cq * 9;
  const float4* wbh =
      (const float4*)wL + (size_t)16 * SLABX + (size_t)slice * SLABH + cq * 9;

  float bz[4];
#pragma unroll
  for (int g = 0; g < 4; ++g) bz[g] = bias[g * H + wg * 4 + wv];
  float cst = 0.f;
  __syncthreads();

  for (int t = 0; t < T; ++t) {
    float acc[64];
#pragma unroll
    for (int c = 0; c < 64; ++c) acc[c] = 0.f;

    if (!XCOH) {
      // layer 0: x static — overlap input projection with waiting for peers
      accum88<QLX>((const float4*)(xin + (size_t)t * DIN * 64) +
                       (size_t)slice * QLX * 64 + bq * 2,
                   wbx, acc);
    }
    // single-lane epoch polls: tid 0 -> own layer (t-1 done); tid 64 -> prev
    if (t > 0 && tid == 0) {
      while (__hip_atomic_load(selfE, __ATOMIC_RELAXED, AGENT) < (unsigned)t)
        __builtin_amdgcn_s_sleep(2);
    }
    if (XCOH && tid == 64) {
      while (__hip_atomic_load(prevE, __ATOMIC_RELAXED, AGENT) <
             (unsigned)(t + 1))
        __builtin_amdgcn_s_sleep(2);
    }
    __syncthreads();
    asm volatile("" ::: "memory");  // no compiler hoist of loads above polls

    if (XCOH) {
      accum88<QLX>((const float4*)(xin + (size_t)t * DIN * 64) +
                       (size_t)slice * QLX * 64 + bq * 2,
                   wbx, acc);
    }
    if (t > 0) {
      accum88<QLH>((const float4*)(hseq + (size_t)(t - 1) * H * 64) +
                       (size_t)slice * QLH * 64 + bq * 2,
                   wbh, acc);
    }

    // ---- intra-wave K-merge ----
    // round 1: xor8 via DPP row_ror:8 (VALU; (i+8)%16 == i^8 for all i)
#pragma unroll
    for (int r = 0; r < 64; ++r) {
      const int v = __builtin_amdgcn_update_dpp(
          0, __float_as_int(acc[r]), 0x128, 0xF, 0xF, false);
      acc[r] += __int_as_float(v);
    }
    // round 2: xor16 via ds_swizzle (crosses DPP rows)
#pragma unroll
    for (int r = 0; r < 64; ++r) {
      const int v = __builtin_amdgcn_ds_swizzle(__float_as_int(acc[r]),
                                                0x401F);  // xor lane^16
      acc[r] += __int_as_float(v);
    }

    // wave partial -> sZ[wv][c][b] (k4==0 lanes carry the merged values)
    if (k4 == 0) {
#pragma unroll
      for (int i = 0; i < 8; ++i) {
#pragma unroll
        for (int h = 0; h < 2; ++h) {
          *(float4*)&sZ[wv][cq * 8 + i][bq * 8 + h * 4] =
              make_float4(acc[i * 8 + h * 4 + 0], acc[i * 8 + h * 4 + 1],
                          acc[i * 8 + h * 4 + 2], acc[i * 8 + h * 4 + 3]);
        }
      }
    }
    __syncthreads();

    float z[4];
#pragma unroll
    for (int g = 0; g < 4; ++g) {
      z[g] = bz[g];
#pragma unroll
      for (int k = 0; k < 4; ++k) z[g] += sZ[k][g * 4 + wv][lane];
    }
    const float ig = 1.f / (1.f + __expf(-z[0]));
    const float fg = 1.f / (1.f + __expf(-z[1]));
    const float gg = FIN ? tanhf(z[2]) : fmaxf(z[2], 0.f);
    const float og = 1.f / (1.f + __expf(-z[3]));
    cst = fg * cst + ig * gg;
    const float ca = FIN ? tanhf(cst) : fmaxf(cst, 0.f);
    const float h = og * ca;
    sH[lane * 4 + wv] = h;  // [b][jl]
    if (FIN && t == T - 1) dout[(size_t)lane * H + wg * 4 + wv] = h;
    __syncthreads();

    // wave 0 publishes the WG's 4 unit-rows in [t][unit][b] layout
    // (agent write-through, coalesced 256B per row), then signals.
    if (wv == 0) {
      float* hw = hseq + (size_t)t * H * 64 + (size_t)(wg * 4) * 64 + lane;
#pragma unroll
      for (int jl = 0; jl < 4; ++jl) {
        __hip_atomic_store(hw + jl * 64, sH[lane * 4 + jl], __ATOMIC_RELAXED,
                           AGENT);
      }
      asm volatile("s_waitcnt vmcnt(0)" ::: "memory");
      if (tid == 0)
        __hip_atomic_store(&selfF[t * NWG + wg], 1u, __ATOMIC_RELAXED, AGENT);
    }
  }
}

__global__ __launch_bounds__(256, 2) void lstm_fused(
    const float* __restrict__ xT, float* __restrict__ h0,
    float* __restrict__ h1, float* __restrict__ h2, float* __restrict__ h3,
    float* __restrict__ h4, float* __restrict__ h5,
    const float* __restrict__ wuT0, const float* __restrict__ wuT1,
    const float* __restrict__ wuT2, const float* __restrict__ wuT3,
    const float* __restrict__ wuT4, const float* __restrict__ wuT5,
    const float* __restrict__ b0, const float* __restrict__ b1,
    const float* __restrict__ b2, const float* __restrict__ b3,
    const float* __restrict__ b4, const float* __restrict__ b5,
    float* __restrict__ dout, unsigned* __restrict__ f0,
    unsigned* __restrict__ f1, unsigned* __restrict__ f2,
    unsigned* __restrict__ f3, unsigned* __restrict__ f4,
    unsigned* __restrict__ f5, unsigned* __restrict__ eps) {
  // max 17*KTq + 64 = 3328 float4s (KTq=192) = 52 KB
  __shared__ alignas(16) float wLDS[4 * 3328];
  __shared__ alignas(16) float sZ[4][16][64];  // 16 KB
  __shared__ alignas(16) float sH[256];        // 1 KB
  // ~70 KB/WG -> 2 blocks/CU; 470 blocks co-resident (sync safe).
  const int b = blockIdx.x;
  const int tid = threadIdx.x;
  // heavy layers (L0, L4) first so they land one-per-CU; aggregators last
  if (b < 128) {
    layer_body<256, 512, 128, false, false>(b, tid, xT, h0, wuT0, b0, nullptr,
                                            f0, eps + 0, nullptr, wLDS, sZ, sH);
  } else if (b < 256) {
    layer_body<256, 512, 128, false, true>(b - 128, tid, h3, h4, wuT4, b4,
                                           nullptr, f4, eps + 4, eps + 3, wLDS,
                                           sZ, sH);
  } else if (b < 320) {
    layer_body<512, 256, 64, false, true>(b - 256, tid, h0, h1, wuT1, b1,
                                          nullptr, f1, eps + 1, eps + 0, wLDS,
                                          sZ, sH);
  } else if (b < 384) {
    layer_body<64, 256, 64, false, true>(b - 320, tid, h2, h3, wuT3, b3,
                                         nullptr, f3, eps + 3, eps + 2, wLDS,
                                         sZ, sH);
  } else if (b < 448) {
    layer_body<512, 256, 64, true, true>(b - 384, tid, h4, h5, wuT5, b5, dout,
                                         f5, eps + 5, eps + 4, wLDS, sZ, sH);
  } else if (b < 464) {
    layer_body<256, 64, 16, false, true>(b - 448, tid, h1, h2, wuT2, b2,
                                         nullptr, f2, eps + 2, eps + 1, wLDS,
                                         sZ, sH);
  } else {
    const int l = b - 464;
    if (l == 0) agg_body<128>(f0, eps + 0);
    else if (l == 1) agg_body<64>(f1, eps + 1);
    else if (l == 2) agg_body<16>(f2, eps + 2);
    else if (l == 3) agg_body<64>(f3, eps + 3);
    else if (l == 4) agg_body<128>(f4, eps + 4);
    else agg_body<64>(f5, eps + 5);
  }
}

extern "C" void kernel_launch(void* const* d_in, const int* in_sizes, int n_in,
                              void* d_out, int out_size, void* d_ws,
                              size_t ws_size, hipStream_t stream) {
  (void)in_sizes; (void)n_in; (void)out_size; (void)ws_size;
  const float* x = (const float*)d_in[0];
  const float* W[6];
  const float* U[6];
  const float* B[6];
  for (int l = 0; l < 6; ++l) {
    W[l] = (const float*)d_in[1 + 3 * l];
    U[l] = (const float*)d_in[2 + 3 * l];
    B[l] = (const float*)d_in[3 + 3 * l];
  }
  char* ws = (char*)d_ws;
  // flags: [T][NWG] per layer; NWG = 128,64,16,64,128,64; then 6 epochs
  unsigned* f0 = (unsigned*)ws;
  unsigned* f1 = f0 + 128 * 256;
  unsigned* f2 = f1 + 64 * 256;
  unsigned* f3 = f2 + 16 * 256;
  unsigned* f4 = f3 + 64 * 256;
  unsigned* f5 = f4 + 128 * 256;
  unsigned* eps = f0 + 464 * 256;
  float* wuT0 = (float*)(ws + (1u << 20));
  float* wuT1 = wuT0 + (size_t)2048 * 768;
  float* wuT2 = wuT1 + (size_t)1024 * 768;
  float* wuT3 = wuT2 + (size_t)256 * 320;
  float* wuT4 = wuT3 + (size_t)1024 * 320;
  float* wuT5 = wuT4 + (size_t)2048 * 768;
  float* xT = (float*)(ws + (22u << 20));   // 16 MB
  float* h0 = (float*)(ws + (38u << 20));   // 32 MB
  float* h1 = (float*)(ws + (70u << 20));   // 16 MB
  float* h2 = (float*)(ws + (86u << 20));   // 4 MB
  float* h3 = (float*)(ws + (90u << 20));   // 16 MB
  float* h4 = (float*)(ws + (106u << 20));  // 32 MB
  float* h5 = (float*)(ws + (138u << 20));  // 16 MB (full T, no ring)

  hipMemsetAsync(f0, 0, (464 * 256 + 8) * sizeof(unsigned), stream);
  xpose_in<<<256, 256, 0, stream>>>(x, xT);
  pack_wu<<<dim3(32, 12), 256, 0, stream>>>(W[0], U[0], wuT0, 256, 512);
  pack_wu<<<dim3(16, 12), 256, 0, stream>>>(W[1], U[1], wuT1, 512, 256);
  pack_wu<<<dim3(4, 5), 256, 0, stream>>>(W[2], U[2], wuT2, 256, 64);
  pack_wu<<<dim3(16, 5), 256, 0, stream>>>(W[3], U[3], wuT3, 64, 256);
  pack_wu<<<dim3(32, 12), 256, 0, stream>>>(W[4], U[4], wuT4, 256, 512);
  pack_wu<<<dim3(16, 12), 256, 0, stream>>>(W[5], U[5], wuT5, 512, 256);

  lstm_fused<<<470, 256, 0, stream>>>(xT, h0, h1, h2, h3, h4, h5, wuT0, wuT1,
                                      wuT2, wuT3, wuT4, wuT5, B[0], B[1], B[2],
                                      B[3], B[4], B[5], (float*)d_out, f0, f1,
                                      f2, f3, f4, f5, eps);
}